// Round 1
// 418.242 us; speedup vs baseline: 1.1161x; 1.1161x over previous
//
#include <hip/hip_runtime.h>
#include <math.h>

#define CH 1024
#define HWSZ 4096   // 64*64
#define NB 16
#define NSLOT 20    // channels actually sampled by the dilated conv

// Native 16B vector (ext_vector_type) — accepted by __builtin_nontemporal_*.
typedef float vfloat4 __attribute__((ext_vector_type(4)));

// Kernel A: per-(b,c) spatial mean for ONLY the 20 channels the dilated conv
// samples: {0..5} (w0 taps), {508..515} (w1 taps), {1018..1023} (w2 taps).
// Output o = c>>7 in [0,8): s[b,o] = w0*y[o-2]{o>=2} + w1*y[o+508] + w2*y[o+1018]{o<=5}.
// Grid = 16*20 = 320 blocks, one plane each; 256 threads x 4 float4 = 4096 floats.
__global__ __launch_bounds__(256) void mean20_kernel(const float* __restrict__ x,
                                                     float* __restrict__ y) {
    const int slot = blockIdx.x % NSLOT;
    const int b = blockIdx.x / NSLOT;
    // slot 0..5 -> c = 0..5 ; slot 6..13 -> c = 508..515 ; slot 14..19 -> c = 1018..1023
    const int c = slot < 6 ? slot : (slot < 14 ? 502 + slot : 1004 + slot);
    const vfloat4* xp = (const vfloat4*)x + ((size_t)b * CH + c) * (HWSZ / 4);
    const int tid = threadIdx.x;
    float s = 0.f;
#pragma unroll
    for (int j = 0; j < 4; ++j) {
        vfloat4 v = xp[tid + 256 * j];
        s += (v.x + v.y) + (v.z + v.w);
    }
    // wave64 down-reduce
#pragma unroll
    for (int off = 32; off > 0; off >>= 1)
        s += __shfl_down(s, off, 64);
    __shared__ float ls[4];
    if ((tid & 63) == 0) ls[tid >> 6] = s;
    __syncthreads();
    if (tid == 0) {
        float t = (ls[0] + ls[1]) + (ls[2] + ls[3]);
        y[b * NSLOT + slot] = t * (1.f / (float)HWSZ);
    }
}

// Kernel B (fused gate + multiply): one block per plane. Every thread
// redundantly computes the block-uniform gate (3 broadcast loads from the
// 1280-float y table, L2-hot, + sigmoid), then scales its 4 float4.
// y table layout: y[b*20 + slot]; for modality group o = c>>7:
//   w0 tap: channel o-2    -> slot o-2   (only o>=2)
//   w1 tap: channel o+508  -> slot 6+o   (always)
//   w2 tap: channel o+1018 -> slot 14+o  (only o<=5)
__global__ __launch_bounds__(256) void mul_kernel(const float* __restrict__ x,
                                                  const float* __restrict__ y,
                                                  const float* __restrict__ w,
                                                  float* __restrict__ out) {
    const int plane = blockIdx.x;          // b*1024 + c
    const int b = plane >> 10;
    const int c = plane & 1023;
    const int o = c >> 7;                  // modality group, block-uniform

    const float* yb = y + b * NSLOT;
    float acc = w[1] * yb[6 + o];
    if (o >= 2) acc += w[0] * yb[o - 2];   // uniform branch, no divergence
    if (o <= 5) acc += w[2] * yb[14 + o];
    const float g = 1.f / (1.f + __expf(-acc));

    const vfloat4* xp = (const vfloat4*)x + (size_t)plane * (HWSZ / 4);
    vfloat4* op = (vfloat4*)out + (size_t)plane * (HWSZ / 4);
    const int tid = threadIdx.x;
#pragma unroll
    for (int j = 0; j < 4; ++j) {
        vfloat4 v = __builtin_nontemporal_load(&xp[tid + 256 * j]);
        v *= g;
        __builtin_nontemporal_store(v, &op[tid + 256 * j]);
    }
}

extern "C" void kernel_launch(void* const* d_in, const int* in_sizes, int n_in,
                              void* d_out, int out_size, void* d_ws, size_t ws_size,
                              hipStream_t stream) {
    const float* x = (const float*)d_in[0];
    const float* w = (const float*)d_in[1];
    float* out = (float*)d_out;

    float* y = (float*)d_ws;              // 16*20 floats

    mean20_kernel<<<NB * NSLOT, 256, 0, stream>>>(x, y);
    mul_kernel<<<NB * CH, 256, 0, stream>>>(x, y, w, out);
}